// Round 5
// baseline (3768.438 us; speedup 1.0000x reference)
//
#include <hip/hip_runtime.h>
#include <math.h>

#define NN 8192
#define DF 768
#define NE_ 262144
#define DIM 1536
#define DSN 16

typedef short short8 __attribute__((ext_vector_type(8)));
typedef float f32x4 __attribute__((ext_vector_type(4)));

__device__ __forceinline__ float bf2f(unsigned short u){
  unsigned int v = ((unsigned int)u) << 16; float f; __builtin_memcpy(&f, &v, 4); return f;
}
__device__ __forceinline__ unsigned short f2bf(float f){
  unsigned int x; __builtin_memcpy(&x, &f, 4);
  x += 0x7fffu + ((x >> 16) & 1u);
  return (unsigned short)(x >> 16);
}
__device__ __forceinline__ float sigmoidf_(float x){ return 1.f/(1.f+expf(-x)); }

// ---------------- prep kernels ----------------

// out[n*Kp+k] = bf16(in[k*N+n]) with zero padding
__global__ void k_transpose_cast(const float* __restrict__ in, unsigned short* __restrict__ out,
                                 int K, int N, int Kp){
  int k = blockIdx.x*256 + threadIdx.x;
  int n = blockIdx.y;
  if (k >= Kp) return;
  unsigned short v = 0;
  if (k < K && n < N) v = f2bf(in[(size_t)k*N + n]);
  out[(size_t)n*Kp + k] = v;
}

// stable rank: pos[i] = #{j : (ts_j, j) < (ts_i, i)}
__global__ __launch_bounds__(256) void k_rank(const int* __restrict__ ts, int* __restrict__ pos){
  __shared__ int sT[256];
  int i = blockIdx.x*256 + threadIdx.x;
  int my = ts[i];
  int r = 0;
  for (int c0 = 0; c0 < NN; c0 += 256){
    sT[threadIdx.x] = ts[c0 + threadIdx.x];
    __syncthreads();
    #pragma unroll 8
    for (int j = 0; j < 256; j++){
      int t = sT[j]; int jj = c0 + j;
      r += (t < my || (t == my && jj < i)) ? 1 : 0;
    }
    __syncthreads();
  }
  pos[i] = r;
}

// seq[pos[i]][:] = bf16(node_feats[i][:])
__global__ void k_gather(const float* __restrict__ nf, const int* __restrict__ pos,
                         unsigned short* __restrict__ seq){
  int i = blockIdx.x; int p = pos[i];
  const float* src = nf + (size_t)i*DF;
  unsigned short* dst = seq + (size_t)p*DF;
  for (int j = threadIdx.x; j < DF; j += 256) dst[j] = f2bf(src[j]);
}

__global__ void k_deg_count(const int* __restrict__ esrc, const int* __restrict__ edst,
                            int* __restrict__ degS, int* __restrict__ degD){
  int e = blockIdx.x*256 + threadIdx.x;
  if (e < NE_){ atomicAdd(&degS[esrc[e]], 1); atomicAdd(&degD[edst[e]], 1); }
}

__global__ void k_norms(const int* __restrict__ degS, const int* __restrict__ degD,
                        float* __restrict__ normS, float* __restrict__ normD){
  int i = blockIdx.x*256 + threadIdx.x;
  if (i < NN){
    normS[i] = rsqrtf(fmaxf((float)degS[i], 1.f));
    normD[i] = rsqrtf(fmaxf((float)degD[i], 1.f));
  }
}

// exclusive scan of deg_in -> row_ptr (and cursor copy); one block of 1024, 8 elems/thread
__global__ __launch_bounds__(1024) void k_rowptr(const int* __restrict__ degD,
                                                 int* __restrict__ row_ptr, int* __restrict__ cursor){
  __shared__ int sp[1024];
  int tid = threadIdx.x;
  int base = tid*8;
  int loc[8]; int s = 0;
  #pragma unroll
  for (int j = 0; j < 8; j++){ loc[j] = degD[base+j]; s += loc[j]; }
  sp[tid] = s; __syncthreads();
  for (int o = 1; o < 1024; o <<= 1){
    int v = (tid >= o) ? sp[tid-o] : 0; __syncthreads();
    sp[tid] += v; __syncthreads();
  }
  int run = sp[tid] - s;   // exclusive
  #pragma unroll
  for (int j = 0; j < 8; j++){ row_ptr[base+j] = run; cursor[base+j] = run; run += loc[j]; }
  if (tid == 1023) row_ptr[NN] = sp[1023];
}

__global__ void k_csr_fill(const int* __restrict__ esrc, const int* __restrict__ edst,
                           int* __restrict__ cursor, int* __restrict__ csr_src){
  int e = blockIdx.x*256 + threadIdx.x;
  if (e < NE_){
    int d = edst[e];
    int p = atomicAdd(&cursor[d], 1);
    csr_src[p] = esrc[e];
  }
}

// ---------------- bf16 MFMA GEMM (128x128 tile, BK=32, 4 waves) ----------------
// A: MxK bf16 row-major (lda). B: NxK bf16 row-major (ldb) i.e. pre-transposed.
// EPI 0: bf16 out. 1: f32 out + bf16 copy of cols<48 into out2 (ld 64, cols 48..63 zero).
// EPI 2: softplus(v + bias[n]) -> f32. 3: gelu_exact(v + bias[n]) -> bf16.
template<int EPI>
__global__ __launch_bounds__(256) void k_gemm(
    const unsigned short* __restrict__ A, const unsigned short* __restrict__ B,
    int N, int K, int lda, int ldb,
    float* __restrict__ outF, int ldoF,
    unsigned short* __restrict__ outB, int ldoB,
    const float* __restrict__ bias,
    unsigned short* __restrict__ out2)
{
  __shared__ unsigned short sA[128][56];  // 56*2=112B row stride: 16B-aligned, ~2-way banks
  __shared__ unsigned short sB[128][56];
  int tid = threadIdx.x;
  int tnc = N >> 7;
  int bm = (blockIdx.x / tnc) << 7;
  int bn = (blockIdx.x % tnc) << 7;
  int wv = tid >> 6, lane = tid & 63;
  int wm = wv >> 1, wn = wv & 1;
  int l15 = lane & 15, l4 = lane >> 4;

  f32x4 acc[4][4];
  #pragma unroll
  for (int i = 0; i < 4; i++)
    #pragma unroll
    for (int j = 0; j < 4; j++)
      acc[i][j] = (f32x4){0.f,0.f,0.f,0.f};

  int r = tid >> 1, hf = tid & 1;
  const unsigned short* gA = A + (size_t)(bm + r)*lda + hf*16;
  const unsigned short* gB = B + (size_t)(bn + r)*ldb + hf*16;

  for (int k0 = 0; k0 < K; k0 += 32){
    short8 va0 = *(const short8*)(gA + k0);
    short8 va1 = *(const short8*)(gA + k0 + 8);
    short8 vb0 = *(const short8*)(gB + k0);
    short8 vb1 = *(const short8*)(gB + k0 + 8);
    __syncthreads();
    *(short8*)&sA[r][hf*16]     = va0;
    *(short8*)&sA[r][hf*16 + 8] = va1;
    *(short8*)&sB[r][hf*16]     = vb0;
    *(short8*)&sB[r][hf*16 + 8] = vb1;
    __syncthreads();
    short8 af[4], bf_[4];
    #pragma unroll
    for (int i = 0; i < 4; i++){
      af[i]  = *(const short8*)&sA[wm*64 + i*16 + l15][l4*8];
      bf_[i] = *(const short8*)&sB[wn*64 + i*16 + l15][l4*8];
    }
    #pragma unroll
    for (int i = 0; i < 4; i++)
      #pragma unroll
      for (int j = 0; j < 4; j++)
        acc[i][j] = __builtin_amdgcn_mfma_f32_16x16x32_bf16(af[i], bf_[j], acc[i][j], 0, 0, 0);
  }

  #pragma unroll
  for (int i = 0; i < 4; i++)
    #pragma unroll
    for (int j = 0; j < 4; j++)
      #pragma unroll
      for (int rr = 0; rr < 4; rr++){
        int row = bm + wm*64 + i*16 + l4*4 + rr;   // C/D: col=lane&15, row=(lane>>4)*4+reg
        int col = bn + wn*64 + j*16 + l15;
        float v = acc[i][j][rr];
        if (EPI == 0){
          outB[(size_t)row*ldoB + col] = f2bf(v);
        } else if (EPI == 1){
          outF[(size_t)row*ldoF + col] = v;
          if (col < 64) out2[(size_t)row*64 + col] = (col < 48) ? f2bf(v) : (unsigned short)0;
        } else if (EPI == 2){
          v += bias[col];
          float sp = (v > 20.f) ? v : log1pf(expf(v));
          outF[(size_t)row*ldoF + col] = sp;
        } else {
          v += bias[col];
          float g = 0.5f*v*(1.f + erff(v*0.70710678118f));
          outB[(size_t)row*ldoB + col] = f2bf(g);
        }
      }
}

// ---------------- causal conv + silu ----------------
__global__ void k_conv_silu(const unsigned short* __restrict__ xz, const float* __restrict__ conv_w,
                            const float* __restrict__ conv_b, unsigned short* __restrict__ u){
  int c = blockIdx.x*256 + threadIdx.x;  // 0..1535
  int t = blockIdx.y;
  float acc = conv_b[c];
  #pragma unroll
  for (int k = 0; k < 4; k++){
    int tt = t - 3 + k;
    if (tt >= 0) acc += bf2f(xz[(size_t)tt*3072 + c]) * conv_w[c*4 + k];
  }
  u[(size_t)t*DIM + c] = f2bf(acc * sigmoidf_(acc));
}

// ---------------- selective scan ----------------
// thread = (channel, state); 16 channels x 16 states per block; 96 blocks.
__global__ __launch_bounds__(256) void k_scan(
    const float* __restrict__ delta, const unsigned short* __restrict__ u,
    const unsigned short* __restrict__ xz, const float* __restrict__ dbc,
    const float* __restrict__ A_log, const float* __restrict__ D_param,
    unsigned short* __restrict__ y)
{
  __shared__ float sD[64][16], sU[64][16], sZ[64][16], sBt[64][16], sCt[64][16];
  int tid = threadIdx.x;
  int s = tid & 15, cl = tid >> 4;
  int c0 = blockIdx.x * 16, c = c0 + cl;
  float Af = -expf(A_log[(size_t)c*DSN + s]);
  float Dc = D_param[c];
  float h = 0.f;
  for (int t0 = 0; t0 < NN; t0 += 64){
    #pragma unroll
    for (int q = 0; q < 4; q++){
      int v = tid + q*256; int rr = v >> 4, cc = v & 15;
      sD[rr][cc]  = delta[(size_t)(t0+rr)*DIM + c0 + cc];
      sU[rr][cc]  = bf2f(u[(size_t)(t0+rr)*DIM + c0 + cc]);
      sZ[rr][cc]  = bf2f(xz[(size_t)(t0+rr)*3072 + 1536 + c0 + cc]);
      sBt[rr][cc] = dbc[(size_t)(t0+rr)*128 + 48 + cc];
      sCt[rr][cc] = dbc[(size_t)(t0+rr)*128 + 64 + cc];
    }
    __syncthreads();
    for (int tt = 0; tt < 64; tt++){
      float dt = sD[tt][cl], uu = sU[tt][cl];
      float dA = __expf(dt * Af);
      h = h*dA + (dt*uu)*sBt[tt][s];
      float p = h * sCt[tt][s];
      p += __shfl_xor(p, 1); p += __shfl_xor(p, 2);
      p += __shfl_xor(p, 4); p += __shfl_xor(p, 8);
      if (s == 0){
        float z = sZ[tt][cl];
        float yv = (p + uu*Dc) * (z * sigmoidf_(z));
        y[(size_t)(t0+tt)*DIM + c] = f2bf(yv);
      }
    }
    __syncthreads();
  }
}

// ---------------- GCN aggregation: m[d] = norm_d[d] * sum_{e:dst=d} h[src]*norm_s[src] ----------------
__global__ __launch_bounds__(192) void k_aggregate(
    const unsigned short* __restrict__ h, const int* __restrict__ row_ptr,
    const int* __restrict__ csr_src, const float* __restrict__ normS,
    const float* __restrict__ normD, unsigned short* __restrict__ m)
{
  int d = blockIdx.x; int tid = threadIdx.x;
  int e0 = row_ptr[d], e1 = row_ptr[d+1];
  float a0 = 0.f, a1 = 0.f, a2 = 0.f, a3 = 0.f;
  for (int e = e0; e < e1; e++){
    int sI = csr_src[e];
    float ns = normS[sI];
    uint2 v = *((const uint2*)(h + (size_t)sI*DF) + tid);
    a0 += bf2f((unsigned short)(v.x & 0xffff)) * ns;
    a1 += bf2f((unsigned short)(v.x >> 16)) * ns;
    a2 += bf2f((unsigned short)(v.y & 0xffff)) * ns;
    a3 += bf2f((unsigned short)(v.y >> 16)) * ns;
  }
  float nd = normD[d];
  uint2 o;
  o.x = (unsigned int)f2bf(a0*nd) | ((unsigned int)f2bf(a1*nd) << 16);
  o.y = (unsigned int)f2bf(a2*nd) | ((unsigned int)f2bf(a3*nd) << 16);
  *((uint2*)(m + (size_t)d*DF) + tid) = o;
}

// ---------------- finals ----------------
__global__ __launch_bounds__(256) void k_causal(const unsigned short* __restrict__ h,
                                                const float* __restrict__ W_c,
                                                const float* __restrict__ b_c,
                                                float* __restrict__ out){
  int wv = threadIdx.x >> 6, lane = threadIdx.x & 63;
  int r = blockIdx.x*4 + wv;
  float s = 0.f;
  #pragma unroll
  for (int j = 0; j < 12; j++){
    int cidx = lane + 64*j;
    s += bf2f(h[(size_t)r*DF + cidx]) * W_c[cidx];
  }
  s += __shfl_xor(s, 32); s += __shfl_xor(s, 16); s += __shfl_xor(s, 8);
  s += __shfl_xor(s, 4);  s += __shfl_xor(s, 2);  s += __shfl_xor(s, 1);
  if (lane == 0){
    float a = s + b_c[0];
    float cz = sigmoidf_(a);
    out[DF + r] = cz;
    out[DF + NN + r] = (cz > 0.7f) ? 1.f : 0.f;
  }
}

__global__ void k_gfeat(const unsigned short* __restrict__ h, float* __restrict__ out){
  int col = blockIdx.x*256 + threadIdx.x;
  int r0 = blockIdx.y * 512;
  float s = 0.f;
  for (int r = r0; r < r0 + 512; r++) s += bf2f(h[(size_t)r*DF + col]);
  atomicAdd(&out[col], s * (1.f/8192.f));
}

// ---------------- launch ----------------
extern "C" void kernel_launch(void* const* d_in, const int* in_sizes, int n_in,
                              void* d_out, int out_size, void* d_ws, size_t ws_size,
                              hipStream_t stream) {
  const float* node_feats = (const float*)d_in[0];
  const int*   timestamps = (const int*)d_in[1];
  const int*   ei         = (const int*)d_in[2];
  const int*   e_src = ei;
  const int*   e_dst = ei + NE_;
  const float* W_in    = (const float*)d_in[3];
  const float* conv_w  = (const float*)d_in[4];
  const float* conv_b  = (const float*)d_in[5];
  const float* W_xproj = (const float*)d_in[6];
  const float* W_dt    = (const float*)d_in[7];
  const float* b_dt    = (const float*)d_in[8];
  const float* A_log   = (const float*)d_in[9];
  const float* D_param = (const float*)d_in[10];
  const float* W_out   = (const float*)d_in[11];
  const float* Wg      = (const float*)d_in[12];
  const float* bg      = (const float*)d_in[13];
  const float* W_c     = (const float*)d_in[14];
  const float* b_c     = (const float*)d_in[15];
  float* out = (float*)d_out;

  char* ws = (char*)d_ws;
  size_t off = 0;
  auto alloc = [&](size_t bytes) -> char* {
    char* p = ws + off; off += (bytes + 255) & ~(size_t)255; return p;
  };
  unsigned short* WinT   = (unsigned short*)alloc((size_t)3072*768*2);
  unsigned short* WxT    = (unsigned short*)alloc((size_t)128*1536*2);
  unsigned short* WdtT   = (unsigned short*)alloc((size_t)1536*64*2);
  unsigned short* WoutT  = (unsigned short*)alloc((size_t)768*1536*2);
  unsigned short* WgT    = (unsigned short*)alloc((size_t)3*768*768*2);
  unsigned short* seq    = (unsigned short*)alloc((size_t)NN*DF*2);
  unsigned short* xz     = (unsigned short*)alloc((size_t)NN*3072*2);
  unsigned short* ubuf   = (unsigned short*)alloc((size_t)NN*DIM*2);
  float*          dbc    = (float*)alloc((size_t)NN*128*4);
  unsigned short* dt48   = (unsigned short*)alloc((size_t)NN*64*2);
  float*          deltaB = (float*)alloc((size_t)NN*DIM*4);
  unsigned short* ybuf   = (unsigned short*)alloc((size_t)NN*DIM*2);
  unsigned short* hbuf   = (unsigned short*)alloc((size_t)NN*DF*2);
  unsigned short* mbuf   = (unsigned short*)alloc((size_t)NN*DF*2);
  int*   pos    = (int*)alloc((size_t)NN*4);
  int*   degS   = (int*)alloc((size_t)2*NN*4);
  int*   degD   = degS + NN;
  float* normS  = (float*)alloc((size_t)NN*4);
  float* normD  = (float*)alloc((size_t)NN*4);
  int*   rowp   = (int*)alloc((size_t)(NN+1)*4);
  int*   cursor = (int*)alloc((size_t)NN*4);
  int*   csr    = (int*)alloc((size_t)NE_*4);

  // zero-init accumulated buffers every call (harness poisons ws/d_out once)
  hipMemsetAsync(degS, 0, (size_t)2*NN*4, stream);
  hipMemsetAsync(out, 0, (size_t)DF*4, stream);

  // weights: transpose+cast (B operands stored N x K row-major, zero-padded)
  k_transpose_cast<<<dim3(3, 3072), 256, 0, stream>>>(W_in, WinT, 768, 3072, 768);
  k_transpose_cast<<<dim3(6, 128),  256, 0, stream>>>(W_xproj, WxT, 1536, 80, 1536);
  k_transpose_cast<<<dim3(1, 1536), 256, 0, stream>>>(W_dt, WdtT, 48, 1536, 64);
  k_transpose_cast<<<dim3(6, 768),  256, 0, stream>>>(W_out, WoutT, 1536, 768, 1536);
  for (int i = 0; i < 3; i++)
    k_transpose_cast<<<dim3(3, 768), 256, 0, stream>>>(Wg + (size_t)i*768*768, WgT + (size_t)i*768*768, 768, 768, 768);

  // sort + gather
  k_rank<<<NN/256, 256, 0, stream>>>(timestamps, pos);
  k_gather<<<NN, 256, 0, stream>>>(node_feats, pos, seq);

  // graph structure
  k_deg_count<<<NE_/256, 256, 0, stream>>>(e_src, e_dst, degS, degD);
  k_norms<<<NN/256, 256, 0, stream>>>(degS, degD, normS, normD);
  k_rowptr<<<1, 1024, 0, stream>>>(degD, rowp, cursor);
  k_csr_fill<<<NE_/256, 256, 0, stream>>>(e_src, e_dst, cursor, csr);

  // G1: xz = seq @ W_in  (8192x3072, K=768)
  k_gemm<0><<<64*24, 256, 0, stream>>>(seq, WinT, 3072, 768, 768, 768,
                                       nullptr, 0, xz, 3072, nullptr, nullptr);
  // conv + silu -> u
  k_conv_silu<<<dim3(6, NN), 256, 0, stream>>>(xz, conv_w, conv_b, ubuf);
  // G2: dbc = u @ W_xproj  (8192x128pad, K=1536); also dt48 bf16 (cols<48)
  k_gemm<1><<<64*1, 256, 0, stream>>>(ubuf, WxT, 128, 1536, 1536, 1536,
                                      dbc, 128, nullptr, 0, nullptr, dt48);
  // G3: delta = softplus(dt48 @ W_dt + b_dt)  (8192x1536, K=64)
  k_gemm<2><<<64*12, 256, 0, stream>>>(dt48, WdtT, 1536, 64, 64, 64,
                                       deltaB, 1536, nullptr, 0, b_dt, nullptr);
  // scan -> y (fused (y + u*D)*silu(z))
  k_scan<<<DIM/16, 256, 0, stream>>>(deltaB, ubuf, xz, dbc, A_log, D_param, ybuf);
  // G4: h = y @ W_out  (8192x768, K=1536)
  k_gemm<0><<<64*6, 256, 0, stream>>>(ybuf, WoutT, 768, 1536, 1536, 1536,
                                      nullptr, 0, hbuf, 768, nullptr, nullptr);
  // 3 GCN layers
  for (int i = 0; i < 3; i++){
    k_aggregate<<<NN, 192, 0, stream>>>(hbuf, rowp, csr, normS, normD, mbuf);
    k_gemm<3><<<64*6, 256, 0, stream>>>(mbuf, WgT + (size_t)i*768*768, 768, 768, 768, 768,
                                        nullptr, 0, hbuf, 768, bg + (size_t)i*768, nullptr);
  }
  // finals
  k_causal<<<NN/4, 256, 0, stream>>>(hbuf, W_c, b_c, out);
  k_gfeat<<<dim3(3, 16), 256, 0, stream>>>(hbuf, out);
}

// Round 6
// 1052.559 us; speedup vs baseline: 3.5803x; 3.5803x over previous
//
#include <hip/hip_runtime.h>
#include <math.h>

#define NN 8192
#define DF 768
#define NE_ 262144
#define DIM 1536
#define DSN 16
#define NCH 64
#define CL  128   // NN / NCH

typedef short short8 __attribute__((ext_vector_type(8)));
typedef float f32x4 __attribute__((ext_vector_type(4)));

__device__ __forceinline__ float bf2f(unsigned short u){
  unsigned int v = ((unsigned int)u) << 16; float f; __builtin_memcpy(&f, &v, 4); return f;
}
__device__ __forceinline__ unsigned short f2bf(float f){
  unsigned int x; __builtin_memcpy(&x, &f, 4);
  x += 0x7fffu + ((x >> 16) & 1u);
  return (unsigned short)(x >> 16);
}
__device__ __forceinline__ float sigmoidf_(float x){ return 1.f/(1.f+expf(-x)); }

// ---------------- prep kernels ----------------

// out[n*Kp+k] = bf16(in[k*N+n]) with zero padding
__global__ void k_transpose_cast(const float* __restrict__ in, unsigned short* __restrict__ out,
                                 int K, int N, int Kp){
  int k = blockIdx.x*256 + threadIdx.x;
  int n = blockIdx.y;
  if (k >= Kp) return;
  unsigned short v = 0;
  if (k < K && n < N) v = f2bf(in[(size_t)k*N + n]);
  out[(size_t)n*Kp + k] = v;
}

// stable rank: pos[i] = #{j : (ts_j, j) < (ts_i, i)}
__global__ __launch_bounds__(256) void k_rank(const int* __restrict__ ts, int* __restrict__ pos){
  __shared__ int sT[256];
  int i = blockIdx.x*256 + threadIdx.x;
  int my = ts[i];
  int r = 0;
  for (int c0 = 0; c0 < NN; c0 += 256){
    sT[threadIdx.x] = ts[c0 + threadIdx.x];
    __syncthreads();
    #pragma unroll 8
    for (int j = 0; j < 256; j++){
      int t = sT[j]; int jj = c0 + j;
      r += (t < my || (t == my && jj < i)) ? 1 : 0;
    }
    __syncthreads();
  }
  pos[i] = r;
}

// seq[pos[i]][:] = bf16(node_feats[i][:])
__global__ void k_gather(const float* __restrict__ nf, const int* __restrict__ pos,
                         unsigned short* __restrict__ seq){
  int i = blockIdx.x; int p = pos[i];
  const float* src = nf + (size_t)i*DF;
  unsigned short* dst = seq + (size_t)p*DF;
  for (int j = threadIdx.x; j < DF; j += 256) dst[j] = f2bf(src[j]);
}

__global__ void k_deg_count(const int* __restrict__ esrc, const int* __restrict__ edst,
                            int* __restrict__ degS, int* __restrict__ degD){
  int e = blockIdx.x*256 + threadIdx.x;
  if (e < NE_){ atomicAdd(&degS[esrc[e]], 1); atomicAdd(&degD[edst[e]], 1); }
}

__global__ void k_norms(const int* __restrict__ degS, const int* __restrict__ degD,
                        float* __restrict__ normS, float* __restrict__ normD){
  int i = blockIdx.x*256 + threadIdx.x;
  if (i < NN){
    normS[i] = rsqrtf(fmaxf((float)degS[i], 1.f));
    normD[i] = rsqrtf(fmaxf((float)degD[i], 1.f));
  }
}

// exclusive scan of deg_in -> row_ptr (and cursor copy); one block of 1024, 8 elems/thread
__global__ __launch_bounds__(1024) void k_rowptr(const int* __restrict__ degD,
                                                 int* __restrict__ row_ptr, int* __restrict__ cursor){
  __shared__ int sp[1024];
  int tid = threadIdx.x;
  int base = tid*8;
  int loc[8]; int s = 0;
  #pragma unroll
  for (int j = 0; j < 8; j++){ loc[j] = degD[base+j]; s += loc[j]; }
  sp[tid] = s; __syncthreads();
  for (int o = 1; o < 1024; o <<= 1){
    int v = (tid >= o) ? sp[tid-o] : 0; __syncthreads();
    sp[tid] += v; __syncthreads();
  }
  int run = sp[tid] - s;   // exclusive
  #pragma unroll
  for (int j = 0; j < 8; j++){ row_ptr[base+j] = run; cursor[base+j] = run; run += loc[j]; }
  if (tid == 1023) row_ptr[NN] = sp[1023];
}

__global__ void k_csr_fill(const int* __restrict__ esrc, const int* __restrict__ edst,
                           int* __restrict__ cursor, int* __restrict__ csr_src){
  int e = blockIdx.x*256 + threadIdx.x;
  if (e < NE_){
    int d = edst[e];
    int p = atomicAdd(&cursor[d], 1);
    csr_src[p] = esrc[e];
  }
}

// ---------------- bf16 MFMA GEMM (128x128 tile, BK=32, 4 waves) ----------------
template<int EPI>
__global__ __launch_bounds__(256) void k_gemm(
    const unsigned short* __restrict__ A, const unsigned short* __restrict__ B,
    int N, int K, int lda, int ldb,
    float* __restrict__ outF, int ldoF,
    unsigned short* __restrict__ outB, int ldoB,
    const float* __restrict__ bias,
    unsigned short* __restrict__ out2)
{
  __shared__ unsigned short sA[128][56];
  __shared__ unsigned short sB[128][56];
  int tid = threadIdx.x;
  int tnc = N >> 7;
  int bm = (blockIdx.x / tnc) << 7;
  int bn = (blockIdx.x % tnc) << 7;
  int wv = tid >> 6, lane = tid & 63;
  int wm = wv >> 1, wn = wv & 1;
  int l15 = lane & 15, l4 = lane >> 4;

  f32x4 acc[4][4];
  #pragma unroll
  for (int i = 0; i < 4; i++)
    #pragma unroll
    for (int j = 0; j < 4; j++)
      acc[i][j] = (f32x4){0.f,0.f,0.f,0.f};

  int r = tid >> 1, hf = tid & 1;
  const unsigned short* gA = A + (size_t)(bm + r)*lda + hf*16;
  const unsigned short* gB = B + (size_t)(bn + r)*ldb + hf*16;

  for (int k0 = 0; k0 < K; k0 += 32){
    short8 va0 = *(const short8*)(gA + k0);
    short8 va1 = *(const short8*)(gA + k0 + 8);
    short8 vb0 = *(const short8*)(gB + k0);
    short8 vb1 = *(const short8*)(gB + k0 + 8);
    __syncthreads();
    *(short8*)&sA[r][hf*16]     = va0;
    *(short8*)&sA[r][hf*16 + 8] = va1;
    *(short8*)&sB[r][hf*16]     = vb0;
    *(short8*)&sB[r][hf*16 + 8] = vb1;
    __syncthreads();
    short8 af[4], bf_[4];
    #pragma unroll
    for (int i = 0; i < 4; i++){
      af[i]  = *(const short8*)&sA[wm*64 + i*16 + l15][l4*8];
      bf_[i] = *(const short8*)&sB[wn*64 + i*16 + l15][l4*8];
    }
    #pragma unroll
    for (int i = 0; i < 4; i++)
      #pragma unroll
      for (int j = 0; j < 4; j++)
        acc[i][j] = __builtin_amdgcn_mfma_f32_16x16x32_bf16(af[i], bf_[j], acc[i][j], 0, 0, 0);
  }

  #pragma unroll
  for (int i = 0; i < 4; i++)
    #pragma unroll
    for (int j = 0; j < 4; j++)
      #pragma unroll
      for (int rr = 0; rr < 4; rr++){
        int row = bm + wm*64 + i*16 + l4*4 + rr;
        int col = bn + wn*64 + j*16 + l15;
        float v = acc[i][j][rr];
        if (EPI == 0){
          outB[(size_t)row*ldoB + col] = f2bf(v);
        } else if (EPI == 1){
          outF[(size_t)row*ldoF + col] = v;
          if (col < 64) out2[(size_t)row*64 + col] = (col < 48) ? f2bf(v) : (unsigned short)0;
        } else if (EPI == 2){
          v += bias[col];
          float sp = (v > 20.f) ? v : log1pf(expf(v));
          outF[(size_t)row*ldoF + col] = sp;
        } else {
          v += bias[col];
          float g = 0.5f*v*(1.f + erff(v*0.70710678118f));
          outB[(size_t)row*ldoB + col] = f2bf(g);
        }
      }
}

// ---------------- causal conv + silu ----------------
__global__ void k_conv_silu(const unsigned short* __restrict__ xz, const float* __restrict__ conv_w,
                            const float* __restrict__ conv_b, unsigned short* __restrict__ u){
  int c = blockIdx.x*256 + threadIdx.x;  // 0..1535
  int t = blockIdx.y;
  float acc = conv_b[c];
  #pragma unroll
  for (int k = 0; k < 4; k++){
    int tt = t - 3 + k;
    if (tt >= 0) acc += bf2f(xz[(size_t)tt*3072 + c]) * conv_w[c*4 + k];
  }
  u[(size_t)t*DIM + c] = f2bf(acc * sigmoidf_(acc));
}

// ---------------- selective scan: chunked parallel (3 phases) ----------------
// thread = channel; 16 states in registers; block = 256 channels x chunk blockIdx.y
// Phase A: local scan from h=0; record per-state (h_end, prod dA) for each chunk.
__global__ __launch_bounds__(256) void k_scanA(
    const float* __restrict__ delta, const unsigned short* __restrict__ u,
    const float* __restrict__ dbc, const float* __restrict__ A_log,
    float* __restrict__ hend, float* __restrict__ aprod)
{
  __shared__ float sBC[CL][32];   // [t][0:16]=B, [16:32]=C (contiguous cols 48..79 of dbc)
  int tid = threadIdx.x;
  int c = blockIdx.x*256 + tid;
  int k = blockIdx.y;
  float a[16];
  #pragma unroll
  for (int s = 0; s < 16; s++) a[s] = -expf(A_log[(size_t)c*16 + s]);
  float h[16], ap[16];
  #pragma unroll
  for (int s = 0; s < 16; s++){ h[s] = 0.f; ap[s] = 1.f; }
  for (int idx = tid; idx < CL*32; idx += 256){
    int t = idx >> 5, j = idx & 31;
    sBC[t][j] = dbc[(size_t)(k*CL + t)*128 + 48 + j];
  }
  __syncthreads();
  const float* dp = delta + (size_t)k*CL*DIM + c;
  const unsigned short* up = u + (size_t)k*CL*DIM + c;
  for (int t = 0; t < CL; t++){
    float dt = dp[t*DIM];
    float uu = bf2f(up[t*DIM]);
    float dtu = dt*uu;
    #pragma unroll
    for (int s = 0; s < 16; s++){
      float dA = __expf(dt*a[s]);
      ap[s] *= dA;
      h[s] = h[s]*dA + dtu*sBC[t][s];
    }
  }
  size_t base = ((size_t)k*DIM + c)*16;
  #pragma unroll
  for (int s = 0; s < 16; s += 4){
    *(f32x4*)&hend[base+s]  = (f32x4){h[s],h[s+1],h[s+2],h[s+3]};
    *(f32x4*)&aprod[base+s] = (f32x4){ap[s],ap[s+1],ap[s+2],ap[s+3]};
  }
}

// Phase B: serial combine over chunks per (c,s); in-place hend -> incoming state per chunk.
__global__ __launch_bounds__(256) void k_scanB(float* __restrict__ hend, const float* __restrict__ aprod){
  int i = blockIdx.x*256 + threadIdx.x;  // 0..24575 = (c,s) flat
  float H = 0.f;
  for (int k = 0; k < NCH; k++){
    size_t o = (size_t)k*DIM*16 + i;
    float e = hend[o], ap = aprod[o];
    hend[o] = H;          // incoming state for chunk k
    H = e + ap*H;         // exact linear-recurrence composition
  }
}

// Phase C: replay chunk from correct incoming state; fuse C-dot + D-skip + silu(z) gate.
__global__ __launch_bounds__(256) void k_scanC(
    const float* __restrict__ delta, const unsigned short* __restrict__ u,
    const unsigned short* __restrict__ xz, const float* __restrict__ dbc,
    const float* __restrict__ A_log, const float* __restrict__ D_param,
    const float* __restrict__ hin, unsigned short* __restrict__ y)
{
  __shared__ float sBC[CL][32];
  int tid = threadIdx.x;
  int c = blockIdx.x*256 + tid;
  int k = blockIdx.y;
  float a[16];
  #pragma unroll
  for (int s = 0; s < 16; s++) a[s] = -expf(A_log[(size_t)c*16 + s]);
  float Dc = D_param[c];
  float h[16];
  size_t base = ((size_t)k*DIM + c)*16;
  #pragma unroll
  for (int s = 0; s < 16; s += 4){
    f32x4 v = *(const f32x4*)&hin[base+s];
    h[s] = v.x; h[s+1] = v.y; h[s+2] = v.z; h[s+3] = v.w;
  }
  for (int idx = tid; idx < CL*32; idx += 256){
    int t = idx >> 5, j = idx & 31;
    sBC[t][j] = dbc[(size_t)(k*CL + t)*128 + 48 + j];
  }
  __syncthreads();
  const float* dp = delta + (size_t)k*CL*DIM + c;
  const unsigned short* up = u + (size_t)k*CL*DIM + c;
  const unsigned short* zp = xz + (size_t)k*CL*3072 + 1536 + c;
  unsigned short* yp = y + (size_t)k*CL*DIM + c;
  for (int t = 0; t < CL; t++){
    float dt = dp[t*DIM];
    float uu = bf2f(up[t*DIM]);
    float zz = bf2f(zp[t*3072]);
    float dtu = dt*uu;
    float acc = 0.f;
    #pragma unroll
    for (int s = 0; s < 16; s++){
      float dA = __expf(dt*a[s]);
      h[s] = h[s]*dA + dtu*sBC[t][s];
      acc += h[s]*sBC[t][16+s];
    }
    float yv = (acc + uu*Dc) * (zz * sigmoidf_(zz));
    yp[t*DIM] = f2bf(yv);
  }
}

// ---------------- GCN aggregation ----------------
__global__ __launch_bounds__(192) void k_aggregate(
    const unsigned short* __restrict__ h, const int* __restrict__ row_ptr,
    const int* __restrict__ csr_src, const float* __restrict__ normS,
    const float* __restrict__ normD, unsigned short* __restrict__ m)
{
  int d = blockIdx.x; int tid = threadIdx.x;
  int e0 = row_ptr[d], e1 = row_ptr[d+1];
  float a0 = 0.f, a1 = 0.f, a2 = 0.f, a3 = 0.f;
  for (int e = e0; e < e1; e++){
    int sI = csr_src[e];
    float ns = normS[sI];
    uint2 v = *((const uint2*)(h + (size_t)sI*DF) + tid);
    a0 += bf2f((unsigned short)(v.x & 0xffff)) * ns;
    a1 += bf2f((unsigned short)(v.x >> 16)) * ns;
    a2 += bf2f((unsigned short)(v.y & 0xffff)) * ns;
    a3 += bf2f((unsigned short)(v.y >> 16)) * ns;
  }
  float nd = normD[d];
  uint2 o;
  o.x = (unsigned int)f2bf(a0*nd) | ((unsigned int)f2bf(a1*nd) << 16);
  o.y = (unsigned int)f2bf(a2*nd) | ((unsigned int)f2bf(a3*nd) << 16);
  *((uint2*)(m + (size_t)d*DF) + tid) = o;
}

// ---------------- finals ----------------
__global__ __launch_bounds__(256) void k_causal(const unsigned short* __restrict__ h,
                                                const float* __restrict__ W_c,
                                                const float* __restrict__ b_c,
                                                float* __restrict__ out){
  int wv = threadIdx.x >> 6, lane = threadIdx.x & 63;
  int r = blockIdx.x*4 + wv;
  float s = 0.f;
  #pragma unroll
  for (int j = 0; j < 12; j++){
    int cidx = lane + 64*j;
    s += bf2f(h[(size_t)r*DF + cidx]) * W_c[cidx];
  }
  s += __shfl_xor(s, 32); s += __shfl_xor(s, 16); s += __shfl_xor(s, 8);
  s += __shfl_xor(s, 4);  s += __shfl_xor(s, 2);  s += __shfl_xor(s, 1);
  if (lane == 0){
    float a = s + b_c[0];
    float cz = sigmoidf_(a);
    out[DF + r] = cz;
    out[DF + NN + r] = (cz > 0.7f) ? 1.f : 0.f;
  }
}

__global__ void k_gfeat(const unsigned short* __restrict__ h, float* __restrict__ out){
  int col = blockIdx.x*256 + threadIdx.x;
  int r0 = blockIdx.y * 512;
  float s = 0.f;
  for (int r = r0; r < r0 + 512; r++) s += bf2f(h[(size_t)r*DF + col]);
  atomicAdd(&out[col], s * (1.f/8192.f));
}

// ---------------- launch ----------------
extern "C" void kernel_launch(void* const* d_in, const int* in_sizes, int n_in,
                              void* d_out, int out_size, void* d_ws, size_t ws_size,
                              hipStream_t stream) {
  const float* node_feats = (const float*)d_in[0];
  const int*   timestamps = (const int*)d_in[1];
  const int*   ei         = (const int*)d_in[2];
  const int*   e_src = ei;
  const int*   e_dst = ei + NE_;
  const float* W_in    = (const float*)d_in[3];
  const float* conv_w  = (const float*)d_in[4];
  const float* conv_b  = (const float*)d_in[5];
  const float* W_xproj = (const float*)d_in[6];
  const float* W_dt    = (const float*)d_in[7];
  const float* b_dt    = (const float*)d_in[8];
  const float* A_log   = (const float*)d_in[9];
  const float* D_param = (const float*)d_in[10];
  const float* W_out   = (const float*)d_in[11];
  const float* Wg      = (const float*)d_in[12];
  const float* bg      = (const float*)d_in[13];
  const float* W_c     = (const float*)d_in[14];
  const float* b_c     = (const float*)d_in[15];
  float* out = (float*)d_out;

  char* ws = (char*)d_ws;
  size_t off = 0;
  auto alloc = [&](size_t bytes) -> char* {
    char* p = ws + off; off += (bytes + 255) & ~(size_t)255; return p;
  };
  unsigned short* WinT   = (unsigned short*)alloc((size_t)3072*768*2);
  unsigned short* WxT    = (unsigned short*)alloc((size_t)128*1536*2);
  unsigned short* WdtT   = (unsigned short*)alloc((size_t)1536*64*2);
  unsigned short* WoutT  = (unsigned short*)alloc((size_t)768*1536*2);
  unsigned short* WgT    = (unsigned short*)alloc((size_t)3*768*768*2);
  unsigned short* seq    = (unsigned short*)alloc((size_t)NN*DF*2);
  unsigned short* xz     = (unsigned short*)alloc((size_t)NN*3072*2);
  unsigned short* ubuf   = (unsigned short*)alloc((size_t)NN*DIM*2);
  float*          dbc    = (float*)alloc((size_t)NN*128*4);
  unsigned short* dt48   = (unsigned short*)alloc((size_t)NN*64*2);
  float*          deltaB = (float*)alloc((size_t)NN*DIM*4);
  unsigned short* ybuf   = (unsigned short*)alloc((size_t)NN*DIM*2);
  unsigned short* hbuf   = (unsigned short*)alloc((size_t)NN*DF*2);
  unsigned short* mbuf   = (unsigned short*)alloc((size_t)NN*DF*2);
  int*   pos    = (int*)alloc((size_t)NN*4);
  int*   degS   = (int*)alloc((size_t)2*NN*4);
  int*   degD   = degS + NN;
  float* normS  = (float*)alloc((size_t)NN*4);
  float* normD  = (float*)alloc((size_t)NN*4);
  int*   rowp   = (int*)alloc((size_t)(NN+1)*4);
  int*   cursor = (int*)alloc((size_t)NN*4);
  int*   csr    = (int*)alloc((size_t)NE_*4);

  // scan chunk summaries alias seq (seq is dead after G1; sizes match exactly: 2*6.29MB = 12.58MB)
  float* hend  = (float*)seq;
  float* aprod = hend + (size_t)NCH*DIM*16;

  // zero-init accumulated buffers every call (harness poisons ws/d_out once)
  hipMemsetAsync(degS, 0, (size_t)2*NN*4, stream);
  hipMemsetAsync(out, 0, (size_t)DF*4, stream);

  // weights: transpose+cast (B operands stored N x K row-major, zero-padded)
  k_transpose_cast<<<dim3(3, 3072), 256, 0, stream>>>(W_in, WinT, 768, 3072, 768);
  k_transpose_cast<<<dim3(6, 128),  256, 0, stream>>>(W_xproj, WxT, 1536, 80, 1536);
  k_transpose_cast<<<dim3(1, 1536), 256, 0, stream>>>(W_dt, WdtT, 48, 1536, 64);
  k_transpose_cast<<<dim3(6, 768),  256, 0, stream>>>(W_out, WoutT, 1536, 768, 1536);
  for (int i = 0; i < 3; i++)
    k_transpose_cast<<<dim3(3, 768), 256, 0, stream>>>(Wg + (size_t)i*768*768, WgT + (size_t)i*768*768, 768, 768, 768);

  // sort + gather
  k_rank<<<NN/256, 256, 0, stream>>>(timestamps, pos);
  k_gather<<<NN, 256, 0, stream>>>(node_feats, pos, seq);

  // graph structure
  k_deg_count<<<NE_/256, 256, 0, stream>>>(e_src, e_dst, degS, degD);
  k_norms<<<NN/256, 256, 0, stream>>>(degS, degD, normS, normD);
  k_rowptr<<<1, 1024, 0, stream>>>(degD, rowp, cursor);
  k_csr_fill<<<NE_/256, 256, 0, stream>>>(e_src, e_dst, cursor, csr);

  // G1: xz = seq @ W_in  (8192x3072, K=768)
  k_gemm<0><<<64*24, 256, 0, stream>>>(seq, WinT, 3072, 768, 768, 768,
                                       nullptr, 0, xz, 3072, nullptr, nullptr);
  // conv + silu -> u
  k_conv_silu<<<dim3(6, NN), 256, 0, stream>>>(xz, conv_w, conv_b, ubuf);
  // G2: dbc = u @ W_xproj  (8192x128pad, K=1536); also dt48 bf16 (cols<48)
  k_gemm<1><<<64*1, 256, 0, stream>>>(ubuf, WxT, 128, 1536, 1536, 1536,
                                      dbc, 128, nullptr, 0, nullptr, dt48);
  // G3: delta = softplus(dt48 @ W_dt + b_dt)  (8192x1536, K=64)
  k_gemm<2><<<64*12, 256, 0, stream>>>(dt48, WdtT, 1536, 64, 64, 64,
                                       deltaB, 1536, nullptr, 0, b_dt, nullptr);
  // chunked scan -> y (fused (y + u*D)*silu(z))
  k_scanA<<<dim3(6, NCH), 256, 0, stream>>>(deltaB, ubuf, dbc, A_log, hend, aprod);
  k_scanB<<<96, 256, 0, stream>>>(hend, aprod);
  k_scanC<<<dim3(6, NCH), 256, 0, stream>>>(deltaB, ubuf, xz, dbc, A_log, D_param, hend, ybuf);
  // G4: h = y @ W_out  (8192x768, K=1536)
  k_gemm<0><<<64*6, 256, 0, stream>>>(ybuf, WoutT, 768, 1536, 1536, 1536,
                                      nullptr, 0, hbuf, 768, nullptr, nullptr);
  // 3 GCN layers
  for (int i = 0; i < 3; i++){
    k_aggregate<<<NN, 192, 0, stream>>>(hbuf, rowp, csr, normS, normD, mbuf);
    k_gemm<3><<<64*6, 256, 0, stream>>>(mbuf, WgT + (size_t)i*768*768, 768, 768, 768, 768,
                                        nullptr, 0, hbuf, 768, bg + (size_t)i*768, nullptr);
  }
  // finals
  k_causal<<<NN/4, 256, 0, stream>>>(hbuf, W_c, b_c, out);
  k_gfeat<<<dim3(3, 16), 256, 0, stream>>>(hbuf, out);
}

// Round 7
// 868.895 us; speedup vs baseline: 4.3370x; 1.2114x over previous
//
#include <hip/hip_runtime.h>
#include <math.h>

#define NN 8192
#define DF 768
#define NE_ 262144
#define DIM 1536
#define DSN 16
#define NCH 64
#define CL  128   // NN / NCH

typedef short short8 __attribute__((ext_vector_type(8)));
typedef float f32x4 __attribute__((ext_vector_type(4)));

__device__ __forceinline__ float bf2f(unsigned short u){
  unsigned int v = ((unsigned int)u) << 16; float f; __builtin_memcpy(&f, &v, 4); return f;
}
__device__ __forceinline__ unsigned short f2bf(float f){
  unsigned int x; __builtin_memcpy(&x, &f, 4);
  x += 0x7fffu + ((x >> 16) & 1u);
  return (unsigned short)(x >> 16);
}
__device__ __forceinline__ float sigmoidf_(float x){ return 1.f/(1.f+expf(-x)); }

// ---------------- prep kernels ----------------

// out[n*Kp+k] = bf16(in[k*N+n]) with zero padding
__global__ void k_transpose_cast(const float* __restrict__ in, unsigned short* __restrict__ out,
                                 int K, int N, int Kp){
  int k = blockIdx.x*256 + threadIdx.x;
  int n = blockIdx.y;
  if (k >= Kp) return;
  unsigned short v = 0;
  if (k < K && n < N) v = f2bf(in[(size_t)k*N + n]);
  out[(size_t)n*Kp + k] = v;
}

// stable rank, 2D-parallel: block (ic, jc); partial rank over 256 j's + atomicAdd.
// pos must be zeroed before launch.
__global__ __launch_bounds__(256) void k_rank(const int* __restrict__ ts, int* __restrict__ pos){
  __shared__ int sT[256];
  int i = blockIdx.x*256 + threadIdx.x;
  int my = ts[i];
  int c0 = blockIdx.y*256;
  sT[threadIdx.x] = ts[c0 + threadIdx.x];
  __syncthreads();
  int r = 0;
  #pragma unroll 8
  for (int j = 0; j < 256; j++){
    int t = sT[j]; int jj = c0 + j;
    r += (t < my || (t == my && jj < i)) ? 1 : 0;
  }
  atomicAdd(&pos[i], r);
}

// seq[pos[i]][:] = bf16(node_feats[i][:])
__global__ void k_gather(const float* __restrict__ nf, const int* __restrict__ pos,
                         unsigned short* __restrict__ seq){
  int i = blockIdx.x; int p = pos[i];
  const float* src = nf + (size_t)i*DF;
  unsigned short* dst = seq + (size_t)p*DF;
  for (int j = threadIdx.x; j < DF; j += 256) dst[j] = f2bf(src[j]);
}

__global__ void k_deg_count(const int* __restrict__ esrc, const int* __restrict__ edst,
                            int* __restrict__ degS, int* __restrict__ degD){
  int e = blockIdx.x*256 + threadIdx.x;
  if (e < NE_){ atomicAdd(&degS[esrc[e]], 1); atomicAdd(&degD[edst[e]], 1); }
}

__global__ void k_norms(const int* __restrict__ degS, const int* __restrict__ degD,
                        float* __restrict__ normS, float* __restrict__ normD){
  int i = blockIdx.x*256 + threadIdx.x;
  if (i < NN){
    normS[i] = rsqrtf(fmaxf((float)degS[i], 1.f));
    normD[i] = rsqrtf(fmaxf((float)degD[i], 1.f));
  }
}

// exclusive scan of deg_in -> row_ptr (and cursor copy); one block of 1024, 8 elems/thread
__global__ __launch_bounds__(1024) void k_rowptr(const int* __restrict__ degD,
                                                 int* __restrict__ row_ptr, int* __restrict__ cursor){
  __shared__ int sp[1024];
  int tid = threadIdx.x;
  int base = tid*8;
  int loc[8]; int s = 0;
  #pragma unroll
  for (int j = 0; j < 8; j++){ loc[j] = degD[base+j]; s += loc[j]; }
  sp[tid] = s; __syncthreads();
  for (int o = 1; o < 1024; o <<= 1){
    int v = (tid >= o) ? sp[tid-o] : 0; __syncthreads();
    sp[tid] += v; __syncthreads();
  }
  int run = sp[tid] - s;   // exclusive
  #pragma unroll
  for (int j = 0; j < 8; j++){ row_ptr[base+j] = run; cursor[base+j] = run; run += loc[j]; }
  if (tid == 1023) row_ptr[NN] = sp[1023];
}

__global__ void k_csr_fill(const int* __restrict__ esrc, const int* __restrict__ edst,
                           int* __restrict__ cursor, int* __restrict__ csr_src){
  int e = blockIdx.x*256 + threadIdx.x;
  if (e < NE_){
    int d = edst[e];
    int p = atomicAdd(&cursor[d], 1);
    csr_src[p] = esrc[e];
  }
}

// ---------------- bf16 MFMA GEMM (128x128 tile, BK=32, 4 waves) ----------------
template<int EPI>
__global__ __launch_bounds__(256) void k_gemm(
    const unsigned short* __restrict__ A, const unsigned short* __restrict__ B,
    int N, int K, int lda, int ldb,
    float* __restrict__ outF, int ldoF,
    unsigned short* __restrict__ outB, int ldoB,
    const float* __restrict__ bias,
    unsigned short* __restrict__ out2)
{
  __shared__ unsigned short sA[128][56];
  __shared__ unsigned short sB[128][56];
  int tid = threadIdx.x;
  int tnc = N >> 7;
  int bm = (blockIdx.x / tnc) << 7;
  int bn = (blockIdx.x % tnc) << 7;
  int wv = tid >> 6, lane = tid & 63;
  int wm = wv >> 1, wn = wv & 1;
  int l15 = lane & 15, l4 = lane >> 4;

  f32x4 acc[4][4];
  #pragma unroll
  for (int i = 0; i < 4; i++)
    #pragma unroll
    for (int j = 0; j < 4; j++)
      acc[i][j] = (f32x4){0.f,0.f,0.f,0.f};

  int r = tid >> 1, hf = tid & 1;
  const unsigned short* gA = A + (size_t)(bm + r)*lda + hf*16;
  const unsigned short* gB = B + (size_t)(bn + r)*ldb + hf*16;

  for (int k0 = 0; k0 < K; k0 += 32){
    short8 va0 = *(const short8*)(gA + k0);
    short8 va1 = *(const short8*)(gA + k0 + 8);
    short8 vb0 = *(const short8*)(gB + k0);
    short8 vb1 = *(const short8*)(gB + k0 + 8);
    __syncthreads();
    *(short8*)&sA[r][hf*16]     = va0;
    *(short8*)&sA[r][hf*16 + 8] = va1;
    *(short8*)&sB[r][hf*16]     = vb0;
    *(short8*)&sB[r][hf*16 + 8] = vb1;
    __syncthreads();
    short8 af[4], bf_[4];
    #pragma unroll
    for (int i = 0; i < 4; i++){
      af[i]  = *(const short8*)&sA[wm*64 + i*16 + l15][l4*8];
      bf_[i] = *(const short8*)&sB[wn*64 + i*16 + l15][l4*8];
    }
    #pragma unroll
    for (int i = 0; i < 4; i++)
      #pragma unroll
      for (int j = 0; j < 4; j++)
        acc[i][j] = __builtin_amdgcn_mfma_f32_16x16x32_bf16(af[i], bf_[j], acc[i][j], 0, 0, 0);
  }

  #pragma unroll
  for (int i = 0; i < 4; i++)
    #pragma unroll
    for (int j = 0; j < 4; j++)
      #pragma unroll
      for (int rr = 0; rr < 4; rr++){
        int row = bm + wm*64 + i*16 + l4*4 + rr;
        int col = bn + wn*64 + j*16 + l15;
        float v = acc[i][j][rr];
        if (EPI == 0){
          outB[(size_t)row*ldoB + col] = f2bf(v);
        } else if (EPI == 1){
          outF[(size_t)row*ldoF + col] = v;
          if (col < 64) out2[(size_t)row*64 + col] = (col < 48) ? f2bf(v) : (unsigned short)0;
        } else if (EPI == 2){
          v += bias[col];
          float sp = (v > 20.f) ? v : log1pf(expf(v));
          outF[(size_t)row*ldoF + col] = sp;
        } else {
          v += bias[col];
          float g = 0.5f*v*(1.f + erff(v*0.70710678118f));
          outB[(size_t)row*ldoB + col] = f2bf(g);
        }
      }
}

// ---------------- causal conv + silu ----------------
__global__ void k_conv_silu(const unsigned short* __restrict__ xz, const float* __restrict__ conv_w,
                            const float* __restrict__ conv_b, unsigned short* __restrict__ u){
  int c = blockIdx.x*256 + threadIdx.x;  // 0..1535
  int t = blockIdx.y;
  float acc = conv_b[c];
  #pragma unroll
  for (int k = 0; k < 4; k++){
    int tt = t - 3 + k;
    if (tt >= 0) acc += bf2f(xz[(size_t)tt*3072 + c]) * conv_w[c*4 + k];
  }
  u[(size_t)t*DIM + c] = f2bf(acc * sigmoidf_(acc));
}

// ---------------- selective scan: chunked parallel (3 phases) ----------------
__global__ __launch_bounds__(256) void k_scanA(
    const float* __restrict__ delta, const unsigned short* __restrict__ u,
    const float* __restrict__ dbc, const float* __restrict__ A_log,
    float* __restrict__ hend, float* __restrict__ aprod)
{
  __shared__ float sBC[CL][32];   // [t][0:16]=B, [16:32]=C
  int tid = threadIdx.x;
  int c = blockIdx.x*256 + tid;
  int k = blockIdx.y;
  float a[16];
  #pragma unroll
  for (int s = 0; s < 16; s++) a[s] = -expf(A_log[(size_t)c*16 + s]);
  float h[16], ap[16];
  #pragma unroll
  for (int s = 0; s < 16; s++){ h[s] = 0.f; ap[s] = 1.f; }
  for (int idx = tid; idx < CL*32; idx += 256){
    int t = idx >> 5, j = idx & 31;
    sBC[t][j] = dbc[(size_t)(k*CL + t)*128 + 48 + j];
  }
  __syncthreads();
  const float* dp = delta + (size_t)k*CL*DIM + c;
  const unsigned short* up = u + (size_t)k*CL*DIM + c;
  for (int t = 0; t < CL; t++){
    float dt = dp[t*DIM];
    float uu = bf2f(up[t*DIM]);
    float dtu = dt*uu;
    #pragma unroll
    for (int s = 0; s < 16; s++){
      float dA = __expf(dt*a[s]);
      ap[s] *= dA;
      h[s] = h[s]*dA + dtu*sBC[t][s];
    }
  }
  size_t base = ((size_t)k*DIM + c)*16;
  #pragma unroll
  for (int s = 0; s < 16; s += 4){
    *(f32x4*)&hend[base+s]  = (f32x4){h[s],h[s+1],h[s+2],h[s+3]};
    *(f32x4*)&aprod[base+s] = (f32x4){ap[s],ap[s+1],ap[s+2],ap[s+3]};
  }
}

__global__ __launch_bounds__(256) void k_scanB(float* __restrict__ hend, const float* __restrict__ aprod){
  int i = blockIdx.x*256 + threadIdx.x;  // 0..24575 = (c,s) flat
  float H = 0.f;
  for (int k = 0; k < NCH; k++){
    size_t o = (size_t)k*DIM*16 + i;
    float e = hend[o], ap = aprod[o];
    hend[o] = H;          // incoming state for chunk k
    H = e + ap*H;         // exact linear-recurrence composition
  }
}

__global__ __launch_bounds__(256) void k_scanC(
    const float* __restrict__ delta, const unsigned short* __restrict__ u,
    const unsigned short* __restrict__ xz, const float* __restrict__ dbc,
    const float* __restrict__ A_log, const float* __restrict__ D_param,
    const float* __restrict__ hin, unsigned short* __restrict__ y)
{
  __shared__ float sBC[CL][32];
  int tid = threadIdx.x;
  int c = blockIdx.x*256 + tid;
  int k = blockIdx.y;
  float a[16];
  #pragma unroll
  for (int s = 0; s < 16; s++) a[s] = -expf(A_log[(size_t)c*16 + s]);
  float Dc = D_param[c];
  float h[16];
  size_t base = ((size_t)k*DIM + c)*16;
  #pragma unroll
  for (int s = 0; s < 16; s += 4){
    f32x4 v = *(const f32x4*)&hin[base+s];
    h[s] = v.x; h[s+1] = v.y; h[s+2] = v.z; h[s+3] = v.w;
  }
  for (int idx = tid; idx < CL*32; idx += 256){
    int t = idx >> 5, j = idx & 31;
    sBC[t][j] = dbc[(size_t)(k*CL + t)*128 + 48 + j];
  }
  __syncthreads();
  const float* dp = delta + (size_t)k*CL*DIM + c;
  const unsigned short* up = u + (size_t)k*CL*DIM + c;
  const unsigned short* zp = xz + (size_t)k*CL*3072 + 1536 + c;
  unsigned short* yp = y + (size_t)k*CL*DIM + c;
  for (int t = 0; t < CL; t++){
    float dt = dp[t*DIM];
    float uu = bf2f(up[t*DIM]);
    float zz = bf2f(zp[t*3072]);
    float dtu = dt*uu;
    float acc = 0.f;
    #pragma unroll
    for (int s = 0; s < 16; s++){
      float dA = __expf(dt*a[s]);
      h[s] = h[s]*dA + dtu*sBC[t][s];
      acc += h[s]*sBC[t][16+s];
    }
    float yv = (acc + uu*Dc) * (zz * sigmoidf_(zz));
    yp[t*DIM] = f2bf(yv);
  }
}

// ---------------- GCN aggregation ----------------
__global__ __launch_bounds__(192) void k_aggregate(
    const unsigned short* __restrict__ h, const int* __restrict__ row_ptr,
    const int* __restrict__ csr_src, const float* __restrict__ normS,
    const float* __restrict__ normD, unsigned short* __restrict__ m)
{
  int d = blockIdx.x; int tid = threadIdx.x;
  int e0 = row_ptr[d], e1 = row_ptr[d+1];
  float a0 = 0.f, a1 = 0.f, a2 = 0.f, a3 = 0.f;
  for (int e = e0; e < e1; e++){
    int sI = csr_src[e];
    float ns = normS[sI];
    uint2 v = *((const uint2*)(h + (size_t)sI*DF) + tid);
    a0 += bf2f((unsigned short)(v.x & 0xffff)) * ns;
    a1 += bf2f((unsigned short)(v.x >> 16)) * ns;
    a2 += bf2f((unsigned short)(v.y & 0xffff)) * ns;
    a3 += bf2f((unsigned short)(v.y >> 16)) * ns;
  }
  float nd = normD[d];
  uint2 o;
  o.x = (unsigned int)f2bf(a0*nd) | ((unsigned int)f2bf(a1*nd) << 16);
  o.y = (unsigned int)f2bf(a2*nd) | ((unsigned int)f2bf(a3*nd) << 16);
  *((uint2*)(m + (size_t)d*DF) + tid) = o;
}

// ---------------- finals ----------------
__global__ __launch_bounds__(256) void k_causal(const unsigned short* __restrict__ h,
                                                const float* __restrict__ W_c,
                                                const float* __restrict__ b_c,
                                                float* __restrict__ out){
  int wv = threadIdx.x >> 6, lane = threadIdx.x & 63;
  int r = blockIdx.x*4 + wv;
  float s = 0.f;
  #pragma unroll
  for (int j = 0; j < 12; j++){
    int cidx = lane + 64*j;
    s += bf2f(h[(size_t)r*DF + cidx]) * W_c[cidx];
  }
  s += __shfl_xor(s, 32); s += __shfl_xor(s, 16); s += __shfl_xor(s, 8);
  s += __shfl_xor(s, 4);  s += __shfl_xor(s, 2);  s += __shfl_xor(s, 1);
  if (lane == 0){
    float a = s + b_c[0];
    float cz = sigmoidf_(a);
    out[DF + r] = cz;
    out[DF + NN + r] = (cz > 0.7f) ? 1.f : 0.f;
  }
}

__global__ void k_gfeat(const unsigned short* __restrict__ h, float* __restrict__ out){
  int col = blockIdx.x*256 + threadIdx.x;
  int r0 = blockIdx.y * 512;
  float s = 0.f;
  for (int r = r0; r < r0 + 512; r++) s += bf2f(h[(size_t)r*DF + col]);
  atomicAdd(&out[col], s * (1.f/8192.f));
}

// ---------------- launch ----------------
extern "C" void kernel_launch(void* const* d_in, const int* in_sizes, int n_in,
                              void* d_out, int out_size, void* d_ws, size_t ws_size,
                              hipStream_t stream) {
  const float* node_feats = (const float*)d_in[0];
  const int*   timestamps = (const int*)d_in[1];
  const int*   ei         = (const int*)d_in[2];
  const int*   e_src = ei;
  const int*   e_dst = ei + NE_;
  const float* W_in    = (const float*)d_in[3];
  const float* conv_w  = (const float*)d_in[4];
  const float* conv_b  = (const float*)d_in[5];
  const float* W_xproj = (const float*)d_in[6];
  const float* W_dt    = (const float*)d_in[7];
  const float* b_dt    = (const float*)d_in[8];
  const float* A_log   = (const float*)d_in[9];
  const float* D_param = (const float*)d_in[10];
  const float* W_out   = (const float*)d_in[11];
  const float* Wg      = (const float*)d_in[12];
  const float* bg      = (const float*)d_in[13];
  const float* W_c     = (const float*)d_in[14];
  const float* b_c     = (const float*)d_in[15];
  float* out = (float*)d_out;

  char* ws = (char*)d_ws;
  size_t off = 0;
  auto alloc = [&](size_t bytes) -> char* {
    char* p = ws + off; off += (bytes + 255) & ~(size_t)255; return p;
  };
  unsigned short* WinT   = (unsigned short*)alloc((size_t)3072*768*2);
  unsigned short* WxT    = (unsigned short*)alloc((size_t)128*1536*2);
  unsigned short* WdtT   = (unsigned short*)alloc((size_t)1536*64*2);
  unsigned short* WoutT  = (unsigned short*)alloc((size_t)768*1536*2);
  unsigned short* WgT    = (unsigned short*)alloc((size_t)3*768*768*2);
  unsigned short* seq    = (unsigned short*)alloc((size_t)NN*DF*2);
  unsigned short* xz     = (unsigned short*)alloc((size_t)NN*3072*2);
  unsigned short* ubuf   = (unsigned short*)alloc((size_t)NN*DIM*2);
  float*          dbc    = (float*)alloc((size_t)NN*128*4);
  unsigned short* dt48   = (unsigned short*)alloc((size_t)NN*64*2);
  float*          deltaB = (float*)alloc((size_t)NN*DIM*4);
  unsigned short* ybuf   = (unsigned short*)alloc((size_t)NN*DIM*2);
  unsigned short* hbuf   = (unsigned short*)alloc((size_t)NN*DF*2);
  unsigned short* mbuf   = (unsigned short*)alloc((size_t)NN*DF*2);
  int*   pos    = (int*)alloc((size_t)NN*4);
  int*   degS   = (int*)alloc((size_t)2*NN*4);
  int*   degD   = degS + NN;
  float* normS  = (float*)alloc((size_t)NN*4);
  float* normD  = (float*)alloc((size_t)NN*4);
  int*   rowp   = (int*)alloc((size_t)(NN+1)*4);
  int*   cursor = (int*)alloc((size_t)NN*4);
  int*   csr    = (int*)alloc((size_t)NE_*4);

  // scan chunk summaries alias seq (seq is dead after G1)
  float* hend  = (float*)seq;
  float* aprod = hend + (size_t)NCH*DIM*16;

  // zero-init accumulated buffers every call (harness poisons ws/d_out once)
  hipMemsetAsync(degS, 0, (size_t)2*NN*4, stream);
  hipMemsetAsync(pos, 0, (size_t)NN*4, stream);
  hipMemsetAsync(out, 0, (size_t)DF*4, stream);

  // weights: transpose+cast (B operands stored N x K row-major, zero-padded)
  k_transpose_cast<<<dim3(3, 3072), 256, 0, stream>>>(W_in, WinT, 768, 3072, 768);
  k_transpose_cast<<<dim3(6, 128),  256, 0, stream>>>(W_xproj, WxT, 1536, 80, 1536);
  k_transpose_cast<<<dim3(1, 1536), 256, 0, stream>>>(W_dt, WdtT, 48, 1536, 64);
  k_transpose_cast<<<dim3(6, 768),  256, 0, stream>>>(W_out, WoutT, 1536, 768, 1536);
  for (int i = 0; i < 3; i++)
    k_transpose_cast<<<dim3(3, 768), 256, 0, stream>>>(Wg + (size_t)i*768*768, WgT + (size_t)i*768*768, 768, 768, 768);

  // sort + gather (rank now 2D-parallel: 32x32 blocks)
  k_rank<<<dim3(NN/256, NN/256), 256, 0, stream>>>(timestamps, pos);
  k_gather<<<NN, 256, 0, stream>>>(node_feats, pos, seq);

  // graph structure
  k_deg_count<<<NE_/256, 256, 0, stream>>>(e_src, e_dst, degS, degD);
  k_norms<<<NN/256, 256, 0, stream>>>(degS, degD, normS, normD);
  k_rowptr<<<1, 1024, 0, stream>>>(degD, rowp, cursor);
  k_csr_fill<<<NE_/256, 256, 0, stream>>>(e_src, e_dst, cursor, csr);

  // G1: xz = seq @ W_in  (8192x3072, K=768)
  k_gemm<0><<<64*24, 256, 0, stream>>>(seq, WinT, 3072, 768, 768, 768,
                                       nullptr, 0, xz, 3072, nullptr, nullptr);
  // conv + silu -> u
  k_conv_silu<<<dim3(6, NN), 256, 0, stream>>>(xz, conv_w, conv_b, ubuf);
  // G2: dbc = u @ W_xproj  (8192x128pad, K=1536); also dt48 bf16 (cols<48)
  k_gemm<1><<<64*1, 256, 0, stream>>>(ubuf, WxT, 128, 1536, 1536, 1536,
                                      dbc, 128, nullptr, 0, nullptr, dt48);
  // G3: delta = softplus(dt48 @ W_dt + b_dt)  (8192x1536, K=64)
  k_gemm<2><<<64*12, 256, 0, stream>>>(dt48, WdtT, 1536, 64, 64, 64,
                                       deltaB, 1536, nullptr, 0, b_dt, nullptr);
  // chunked scan -> y (fused (y + u*D)*silu(z))
  k_scanA<<<dim3(6, NCH), 256, 0, stream>>>(deltaB, ubuf, dbc, A_log, hend, aprod);
  k_scanB<<<96, 256, 0, stream>>>(hend, aprod);
  k_scanC<<<dim3(6, NCH), 256, 0, stream>>>(deltaB, ubuf, xz, dbc, A_log, D_param, hend, ybuf);
  // G4: h = y @ W_out  (8192x768, K=1536)
  k_gemm<0><<<64*6, 256, 0, stream>>>(ybuf, WoutT, 768, 1536, 1536, 1536,
                                      nullptr, 0, hbuf, 768, nullptr, nullptr);
  // 3 GCN layers
  for (int i = 0; i < 3; i++){
    k_aggregate<<<NN, 192, 0, stream>>>(hbuf, rowp, csr, normS, normD, mbuf);
    k_gemm<3><<<64*6, 256, 0, stream>>>(mbuf, WgT + (size_t)i*768*768, 768, 768, 768, 768,
                                        nullptr, 0, hbuf, 768, bg + (size_t)i*768, nullptr);
  }
  // finals
  k_causal<<<NN/4, 256, 0, stream>>>(hbuf, W_c, b_c, out);
  k_gfeat<<<dim3(3, 16), 256, 0, stream>>>(hbuf, out);
}

// Round 8
// 804.094 us; speedup vs baseline: 4.6866x; 1.0806x over previous
//
#include <hip/hip_runtime.h>
#include <math.h>

#define NN 8192
#define DF 768
#define NE_ 262144
#define DIM 1536
#define DSN 16
#define NCH 128
#define CL  64   // NN / NCH

typedef short short8 __attribute__((ext_vector_type(8)));
typedef float f32x4 __attribute__((ext_vector_type(4)));

__device__ __forceinline__ float bf2f(unsigned short u){
  unsigned int v = ((unsigned int)u) << 16; float f; __builtin_memcpy(&f, &v, 4); return f;
}
__device__ __forceinline__ unsigned short f2bf(float f){
  unsigned int x; __builtin_memcpy(&x, &f, 4);
  x += 0x7fffu + ((x >> 16) & 1u);
  return (unsigned short)(x >> 16);
}
__device__ __forceinline__ float sigmoidf_(float x){ return 1.f/(1.f+expf(-x)); }

// ---------------- prep kernels ----------------

// out[n*Kp+k] = bf16(in[k*N+n]) with zero padding
__global__ void k_transpose_cast(const float* __restrict__ in, unsigned short* __restrict__ out,
                                 int K, int N, int Kp){
  int k = blockIdx.x*256 + threadIdx.x;
  int n = blockIdx.y;
  if (k >= Kp) return;
  unsigned short v = 0;
  if (k < K && n < N) v = f2bf(in[(size_t)k*N + n]);
  out[(size_t)n*Kp + k] = v;
}

// stable rank, 2D-parallel: block (ic, jc); partial rank over 256 j's + atomicAdd.
__global__ __launch_bounds__(256) void k_rank(const int* __restrict__ ts, int* __restrict__ pos){
  __shared__ int sT[256];
  int i = blockIdx.x*256 + threadIdx.x;
  int my = ts[i];
  int c0 = blockIdx.y*256;
  sT[threadIdx.x] = ts[c0 + threadIdx.x];
  __syncthreads();
  int r = 0;
  #pragma unroll 8
  for (int j = 0; j < 256; j++){
    int t = sT[j]; int jj = c0 + j;
    r += (t < my || (t == my && jj < i)) ? 1 : 0;
  }
  atomicAdd(&pos[i], r);
}

// seq[pos[i]][:] = bf16(node_feats[i][:])
__global__ void k_gather(const float* __restrict__ nf, const int* __restrict__ pos,
                         unsigned short* __restrict__ seq){
  int i = blockIdx.x; int p = pos[i];
  const float* src = nf + (size_t)i*DF;
  unsigned short* dst = seq + (size_t)p*DF;
  for (int j = threadIdx.x; j < DF; j += 256) dst[j] = f2bf(src[j]);
}

__global__ void k_deg_count(const int* __restrict__ esrc, const int* __restrict__ edst,
                            int* __restrict__ degS, int* __restrict__ degD){
  int e = blockIdx.x*256 + threadIdx.x;
  if (e < NE_){ atomicAdd(&degS[esrc[e]], 1); atomicAdd(&degD[edst[e]], 1); }
}

__global__ void k_norms(const int* __restrict__ degS, const int* __restrict__ degD,
                        float* __restrict__ normS, float* __restrict__ normD){
  int i = blockIdx.x*256 + threadIdx.x;
  if (i < NN){
    normS[i] = rsqrtf(fmaxf((float)degS[i], 1.f));
    normD[i] = rsqrtf(fmaxf((float)degD[i], 1.f));
  }
}

// exclusive scan of deg_in -> row_ptr (and cursor copy); one block of 1024, 8 elems/thread
__global__ __launch_bounds__(1024) void k_rowptr(const int* __restrict__ degD,
                                                 int* __restrict__ row_ptr, int* __restrict__ cursor){
  __shared__ int sp[1024];
  int tid = threadIdx.x;
  int base = tid*8;
  int loc[8]; int s = 0;
  #pragma unroll
  for (int j = 0; j < 8; j++){ loc[j] = degD[base+j]; s += loc[j]; }
  sp[tid] = s; __syncthreads();
  for (int o = 1; o < 1024; o <<= 1){
    int v = (tid >= o) ? sp[tid-o] : 0; __syncthreads();
    sp[tid] += v; __syncthreads();
  }
  int run = sp[tid] - s;   // exclusive
  #pragma unroll
  for (int j = 0; j < 8; j++){ row_ptr[base+j] = run; cursor[base+j] = run; run += loc[j]; }
  if (tid == 1023) row_ptr[NN] = sp[1023];
}

__global__ void k_csr_fill(const int* __restrict__ esrc, const int* __restrict__ edst,
                           int* __restrict__ cursor, int* __restrict__ csr_src){
  int e = blockIdx.x*256 + threadIdx.x;
  if (e < NE_){
    int d = edst[e];
    int p = atomicAdd(&cursor[d], 1);
    csr_src[p] = esrc[e];
  }
}

// ---------------- bf16 MFMA GEMM (128x128 tile, BK=32, 4 waves) ----------------
template<int EPI>
__global__ __launch_bounds__(256) void k_gemm(
    const unsigned short* __restrict__ A, const unsigned short* __restrict__ B,
    int N, int K, int lda, int ldb,
    float* __restrict__ outF, int ldoF,
    unsigned short* __restrict__ outB, int ldoB,
    const float* __restrict__ bias,
    unsigned short* __restrict__ out2)
{
  __shared__ unsigned short sA[128][56];
  __shared__ unsigned short sB[128][56];
  int tid = threadIdx.x;
  int tnc = N >> 7;
  int bm = (blockIdx.x / tnc) << 7;
  int bn = (blockIdx.x % tnc) << 7;
  int wv = tid >> 6, lane = tid & 63;
  int wm = wv >> 1, wn = wv & 1;
  int l15 = lane & 15, l4 = lane >> 4;

  f32x4 acc[4][4];
  #pragma unroll
  for (int i = 0; i < 4; i++)
    #pragma unroll
    for (int j = 0; j < 4; j++)
      acc[i][j] = (f32x4){0.f,0.f,0.f,0.f};

  int r = tid >> 1, hf = tid & 1;
  const unsigned short* gA = A + (size_t)(bm + r)*lda + hf*16;
  const unsigned short* gB = B + (size_t)(bn + r)*ldb + hf*16;

  for (int k0 = 0; k0 < K; k0 += 32){
    short8 va0 = *(const short8*)(gA + k0);
    short8 va1 = *(const short8*)(gA + k0 + 8);
    short8 vb0 = *(const short8*)(gB + k0);
    short8 vb1 = *(const short8*)(gB + k0 + 8);
    __syncthreads();
    *(short8*)&sA[r][hf*16]     = va0;
    *(short8*)&sA[r][hf*16 + 8] = va1;
    *(short8*)&sB[r][hf*16]     = vb0;
    *(short8*)&sB[r][hf*16 + 8] = vb1;
    __syncthreads();
    short8 af[4], bf_[4];
    #pragma unroll
    for (int i = 0; i < 4; i++){
      af[i]  = *(const short8*)&sA[wm*64 + i*16 + l15][l4*8];
      bf_[i] = *(const short8*)&sB[wn*64 + i*16 + l15][l4*8];
    }
    #pragma unroll
    for (int i = 0; i < 4; i++)
      #pragma unroll
      for (int j = 0; j < 4; j++)
        acc[i][j] = __builtin_amdgcn_mfma_f32_16x16x32_bf16(af[i], bf_[j], acc[i][j], 0, 0, 0);
  }

  #pragma unroll
  for (int i = 0; i < 4; i++)
    #pragma unroll
    for (int j = 0; j < 4; j++)
      #pragma unroll
      for (int rr = 0; rr < 4; rr++){
        int row = bm + wm*64 + i*16 + l4*4 + rr;
        int col = bn + wn*64 + j*16 + l15;
        float v = acc[i][j][rr];
        if (EPI == 0){
          outB[(size_t)row*ldoB + col] = f2bf(v);
        } else if (EPI == 1){
          outF[(size_t)row*ldoF + col] = v;
          if (col < 64) out2[(size_t)row*64 + col] = (col < 48) ? f2bf(v) : (unsigned short)0;
        } else if (EPI == 2){
          v += bias[col];
          float sp = (v > 20.f) ? v : log1pf(expf(v));
          outF[(size_t)row*ldoF + col] = sp;
        } else {
          v += bias[col];
          float g = 0.5f*v*(1.f + erff(v*0.70710678118f));
          outB[(size_t)row*ldoB + col] = f2bf(g);
        }
      }
}

// ---------------- causal conv + silu ----------------
__global__ void k_conv_silu(const unsigned short* __restrict__ xz, const float* __restrict__ conv_w,
                            const float* __restrict__ conv_b, unsigned short* __restrict__ u){
  int c = blockIdx.x*256 + threadIdx.x;  // 0..1535
  int t = blockIdx.y;
  float acc = conv_b[c];
  #pragma unroll
  for (int k = 0; k < 4; k++){
    int tt = t - 3 + k;
    if (tt >= 0) acc += bf2f(xz[(size_t)tt*3072 + c]) * conv_w[c*4 + k];
  }
  u[(size_t)t*DIM + c] = f2bf(acc * sigmoidf_(acc));
}

// ---------------- selective scan: chunked parallel (3 phases) ----------------
__global__ __launch_bounds__(256) void k_scanA(
    const float* __restrict__ delta, const unsigned short* __restrict__ u,
    const float* __restrict__ dbc, const float* __restrict__ A_log,
    float* __restrict__ hend, float* __restrict__ aprod)
{
  __shared__ float sBC[CL][32];   // [t][0:16]=B, [16:32]=C
  int tid = threadIdx.x;
  int c = blockIdx.x*256 + tid;
  int k = blockIdx.y;
  float a[16];
  #pragma unroll
  for (int s = 0; s < 16; s++) a[s] = -expf(A_log[(size_t)c*16 + s]);
  float h[16];
  #pragma unroll
  for (int s = 0; s < 16; s++) h[s] = 0.f;
  float sdt = 0.f;
  for (int idx = tid; idx < CL*32; idx += 256){
    int t = idx >> 5, j = idx & 31;
    sBC[t][j] = dbc[(size_t)(k*CL + t)*128 + 48 + j];
  }
  __syncthreads();
  const float* dp = delta + (size_t)k*CL*DIM + c;
  const unsigned short* up = u + (size_t)k*CL*DIM + c;
  for (int t = 0; t < CL; t++){
    float dt = dp[t*DIM];
    float uu = bf2f(up[t*DIM]);
    float dtu = dt*uu;
    sdt += dt;
    #pragma unroll
    for (int s = 0; s < 16; s++){
      float dA = __expf(dt*a[s]);
      h[s] = h[s]*dA + dtu*sBC[t][s];
    }
  }
  size_t base = ((size_t)k*DIM + c)*16;
  #pragma unroll
  for (int s = 0; s < 16; s += 4){
    *(f32x4*)&hend[base+s]  = (f32x4){h[s],h[s+1],h[s+2],h[s+3]};
    // prod of exp(dt*a) over chunk == exp(a * sum dt) exactly
    *(f32x4*)&aprod[base+s] = (f32x4){__expf(a[s]*sdt),__expf(a[s+1]*sdt),
                                      __expf(a[s+2]*sdt),__expf(a[s+3]*sdt)};
  }
}

__global__ __launch_bounds__(256) void k_scanB(float* __restrict__ hend, const float* __restrict__ aprod){
  int i = blockIdx.x*256 + threadIdx.x;  // 0..24575 = (c,s) flat
  float H = 0.f;
  for (int k = 0; k < NCH; k++){
    size_t o = (size_t)k*DIM*16 + i;
    float e = hend[o], ap = aprod[o];
    hend[o] = H;          // incoming state for chunk k
    H = e + ap*H;         // exact linear-recurrence composition
  }
}

__global__ __launch_bounds__(256) void k_scanC(
    const float* __restrict__ delta, const unsigned short* __restrict__ u,
    const unsigned short* __restrict__ xz, const float* __restrict__ dbc,
    const float* __restrict__ A_log, const float* __restrict__ D_param,
    const float* __restrict__ hin, unsigned short* __restrict__ y)
{
  __shared__ float sBC[CL][32];
  int tid = threadIdx.x;
  int c = blockIdx.x*256 + tid;
  int k = blockIdx.y;
  float a[16];
  #pragma unroll
  for (int s = 0; s < 16; s++) a[s] = -expf(A_log[(size_t)c*16 + s]);
  float Dc = D_param[c];
  float h[16];
  size_t base = ((size_t)k*DIM + c)*16;
  #pragma unroll
  for (int s = 0; s < 16; s += 4){
    f32x4 v = *(const f32x4*)&hin[base+s];
    h[s] = v.x; h[s+1] = v.y; h[s+2] = v.z; h[s+3] = v.w;
  }
  for (int idx = tid; idx < CL*32; idx += 256){
    int t = idx >> 5, j = idx & 31;
    sBC[t][j] = dbc[(size_t)(k*CL + t)*128 + 48 + j];
  }
  __syncthreads();
  const float* dp = delta + (size_t)k*CL*DIM + c;
  const unsigned short* up = u + (size_t)k*CL*DIM + c;
  const unsigned short* zp = xz + (size_t)k*CL*3072 + 1536 + c;
  unsigned short* yp = y + (size_t)k*CL*DIM + c;
  for (int t = 0; t < CL; t++){
    float dt = dp[t*DIM];
    float uu = bf2f(up[t*DIM]);
    float zz = bf2f(zp[t*3072]);
    float dtu = dt*uu;
    float acc = 0.f;
    #pragma unroll
    for (int s = 0; s < 16; s++){
      float dA = __expf(dt*a[s]);
      h[s] = h[s]*dA + dtu*sBC[t][s];
      acc += h[s]*sBC[t][16+s];
    }
    float yv = (acc + uu*Dc) * (zz * sigmoidf_(zz));
    yp[t*DIM] = f2bf(yv);
  }
}

// ---------------- GCN aggregation ----------------
__global__ __launch_bounds__(192) void k_aggregate(
    const unsigned short* __restrict__ h, const int* __restrict__ row_ptr,
    const int* __restrict__ csr_src, const float* __restrict__ normS,
    const float* __restrict__ normD, unsigned short* __restrict__ m)
{
  int d = blockIdx.x; int tid = threadIdx.x;
  int e0 = row_ptr[d], e1 = row_ptr[d+1];
  float a0 = 0.f, a1 = 0.f, a2 = 0.f, a3 = 0.f;
  for (int e = e0; e < e1; e++){
    int sI = csr_src[e];
    float ns = normS[sI];
    uint2 v = *((const uint2*)(h + (size_t)sI*DF) + tid);
    a0 += bf2f((unsigned short)(v.x & 0xffff)) * ns;
    a1 += bf2f((unsigned short)(v.x >> 16)) * ns;
    a2 += bf2f((unsigned short)(v.y & 0xffff)) * ns;
    a3 += bf2f((unsigned short)(v.y >> 16)) * ns;
  }
  float nd = normD[d];
  uint2 o;
  o.x = (unsigned int)f2bf(a0*nd) | ((unsigned int)f2bf(a1*nd) << 16);
  o.y = (unsigned int)f2bf(a2*nd) | ((unsigned int)f2bf(a3*nd) << 16);
  *((uint2*)(m + (size_t)d*DF) + tid) = o;
}

// ---------------- finals ----------------
__global__ __launch_bounds__(256) void k_causal(const unsigned short* __restrict__ h,
                                                const float* __restrict__ W_c,
                                                const float* __restrict__ b_c,
                                                float* __restrict__ out){
  int wv = threadIdx.x >> 6, lane = threadIdx.x & 63;
  int r = blockIdx.x*4 + wv;
  float s = 0.f;
  #pragma unroll
  for (int j = 0; j < 12; j++){
    int cidx = lane + 64*j;
    s += bf2f(h[(size_t)r*DF + cidx]) * W_c[cidx];
  }
  s += __shfl_xor(s, 32); s += __shfl_xor(s, 16); s += __shfl_xor(s, 8);
  s += __shfl_xor(s, 4);  s += __shfl_xor(s, 2);  s += __shfl_xor(s, 1);
  if (lane == 0){
    float a = s + b_c[0];
    float cz = sigmoidf_(a);
    out[DF + r] = cz;
    out[DF + NN + r] = (cz > 0.7f) ? 1.f : 0.f;
  }
}

__global__ void k_gfeat(const unsigned short* __restrict__ h, float* __restrict__ out){
  int col = blockIdx.x*256 + threadIdx.x;
  int r0 = blockIdx.y * 512;
  float s = 0.f;
  for (int r = r0; r < r0 + 512; r++) s += bf2f(h[(size_t)r*DF + col]);
  atomicAdd(&out[col], s * (1.f/8192.f));
}

// ---------------- launch ----------------
extern "C" void kernel_launch(void* const* d_in, const int* in_sizes, int n_in,
                              void* d_out, int out_size, void* d_ws, size_t ws_size,
                              hipStream_t stream) {
  const float* node_feats = (const float*)d_in[0];
  const int*   timestamps = (const int*)d_in[1];
  const int*   ei         = (const int*)d_in[2];
  const int*   e_src = ei;
  const int*   e_dst = ei + NE_;
  const float* W_in    = (const float*)d_in[3];
  const float* conv_w  = (const float*)d_in[4];
  const float* conv_b  = (const float*)d_in[5];
  const float* W_xproj = (const float*)d_in[6];
  const float* W_dt    = (const float*)d_in[7];
  const float* b_dt    = (const float*)d_in[8];
  const float* A_log   = (const float*)d_in[9];
  const float* D_param = (const float*)d_in[10];
  const float* W_out   = (const float*)d_in[11];
  const float* Wg      = (const float*)d_in[12];
  const float* bg      = (const float*)d_in[13];
  const float* W_c     = (const float*)d_in[14];
  const float* b_c     = (const float*)d_in[15];
  float* out = (float*)d_out;

  char* ws = (char*)d_ws;
  size_t off = 0;
  auto alloc = [&](size_t bytes) -> char* {
    char* p = ws + off; off += (bytes + 255) & ~(size_t)255; return p;
  };
  unsigned short* WinT   = (unsigned short*)alloc((size_t)3072*768*2);
  unsigned short* WxT    = (unsigned short*)alloc((size_t)128*1536*2);
  unsigned short* WdtT   = (unsigned short*)alloc((size_t)1536*64*2);
  unsigned short* WoutT  = (unsigned short*)alloc((size_t)768*1536*2);
  unsigned short* WgT    = (unsigned short*)alloc((size_t)3*768*768*2);
  unsigned short* seq    = (unsigned short*)alloc((size_t)NN*DF*2);
  unsigned short* xz     = (unsigned short*)alloc((size_t)NN*3072*2);
  unsigned short* ubuf   = (unsigned short*)alloc((size_t)NN*DIM*2);
  float*          dbc    = (float*)alloc((size_t)NN*128*4);
  unsigned short* dt48   = (unsigned short*)alloc((size_t)NN*64*2);
  float*          deltaB = (float*)alloc((size_t)NN*DIM*4);
  unsigned short* ybuf   = (unsigned short*)alloc((size_t)NN*DIM*2);
  unsigned short* hbuf   = (unsigned short*)alloc((size_t)NN*DF*2);
  unsigned short* mbuf   = (unsigned short*)alloc((size_t)NN*DF*2);
  int*   pos    = (int*)alloc((size_t)NN*4);
  int*   degS   = (int*)alloc((size_t)2*NN*4);
  int*   degD   = degS + NN;
  float* normS  = (float*)alloc((size_t)NN*4);
  float* normD  = (float*)alloc((size_t)NN*4);
  int*   rowp   = (int*)alloc((size_t)(NN+1)*4);
  int*   cursor = (int*)alloc((size_t)NN*4);
  int*   csr    = (int*)alloc((size_t)NE_*4);

  // scan chunk summaries (NCH=128: 12.58 MB each):
  // hend aliases seq (dead after G1); aprod aliases mbuf (first written by k_aggregate, after scan)
  float* hend  = (float*)seq;
  float* aprod = (float*)mbuf;

  // zero-init accumulated buffers every call (harness poisons ws/d_out once)
  hipMemsetAsync(degS, 0, (size_t)2*NN*4, stream);
  hipMemsetAsync(pos, 0, (size_t)NN*4, stream);
  hipMemsetAsync(out, 0, (size_t)DF*4, stream);

  // weights: transpose+cast (B operands stored N x K row-major, zero-padded)
  k_transpose_cast<<<dim3(3, 3072), 256, 0, stream>>>(W_in, WinT, 768, 3072, 768);
  k_transpose_cast<<<dim3(6, 128),  256, 0, stream>>>(W_xproj, WxT, 1536, 80, 1536);
  k_transpose_cast<<<dim3(1, 1536), 256, 0, stream>>>(W_dt, WdtT, 48, 1536, 64);
  k_transpose_cast<<<dim3(6, 768),  256, 0, stream>>>(W_out, WoutT, 1536, 768, 1536);
  for (int i = 0; i < 3; i++)
    k_transpose_cast<<<dim3(3, 768), 256, 0, stream>>>(Wg + (size_t)i*768*768, WgT + (size_t)i*768*768, 768, 768, 768);

  // sort + gather (rank 2D-parallel: 32x32 blocks)
  k_rank<<<dim3(NN/256, NN/256), 256, 0, stream>>>(timestamps, pos);
  k_gather<<<NN, 256, 0, stream>>>(node_feats, pos, seq);

  // graph structure
  k_deg_count<<<NE_/256, 256, 0, stream>>>(e_src, e_dst, degS, degD);
  k_norms<<<NN/256, 256, 0, stream>>>(degS, degD, normS, normD);
  k_rowptr<<<1, 1024, 0, stream>>>(degD, rowp, cursor);
  k_csr_fill<<<NE_/256, 256, 0, stream>>>(e_src, e_dst, cursor, csr);

  // G1: xz = seq @ W_in  (8192x3072, K=768)
  k_gemm<0><<<64*24, 256, 0, stream>>>(seq, WinT, 3072, 768, 768, 768,
                                       nullptr, 0, xz, 3072, nullptr, nullptr);
  // conv + silu -> u
  k_conv_silu<<<dim3(6, NN), 256, 0, stream>>>(xz, conv_w, conv_b, ubuf);
  // G2: dbc = u @ W_xproj  (8192x128pad, K=1536); also dt48 bf16 (cols<48)
  k_gemm<1><<<64*1, 256, 0, stream>>>(ubuf, WxT, 128, 1536, 1536, 1536,
                                      dbc, 128, nullptr, 0, nullptr, dt48);
  // G3: delta = softplus(dt48 @ W_dt + b_dt)  (8192x1536, K=64)
  k_gemm<2><<<64*12, 256, 0, stream>>>(dt48, WdtT, 1536, 64, 64, 64,
                                       deltaB, 1536, nullptr, 0, b_dt, nullptr);
  // chunked scan -> y (fused (y + u*D)*silu(z))
  k_scanA<<<dim3(6, NCH), 256, 0, stream>>>(deltaB, ubuf, dbc, A_log, hend, aprod);
  k_scanB<<<96, 256, 0, stream>>>(hend, aprod);
  k_scanC<<<dim3(6, NCH), 256, 0, stream>>>(deltaB, ubuf, xz, dbc, A_log, D_param, hend, ybuf);
  // G4: h = y @ W_out  (8192x768, K=1536)
  k_gemm<0><<<64*6, 256, 0, stream>>>(ybuf, WoutT, 768, 1536, 1536, 1536,
                                      nullptr, 0, hbuf, 768, nullptr, nullptr);
  // 3 GCN layers
  for (int i = 0; i < 3; i++){
    k_aggregate<<<NN, 192, 0, stream>>>(hbuf, rowp, csr, normS, normD, mbuf);
    k_gemm<3><<<64*6, 256, 0, stream>>>(mbuf, WgT + (size_t)i*768*768, 768, 768, 768, 768,
                                        nullptr, 0, hbuf, 768, bg + (size_t)i*768, nullptr);
  }
  // finals
  k_causal<<<NN/4, 256, 0, stream>>>(hbuf, W_c, b_c, out);
  k_gfeat<<<dim3(3, 16), 256, 0, stream>>>(hbuf, out);
}